// Round 6
// baseline (6551.260 us; speedup 1.0000x reference)
//
#include <hip/hip_runtime.h>

// NODE scan: 32 groups x 8 blocks; group = 16 batch rows; block j owns a
// 64-col slice of W1/W2, 64-ROW slice of W3 (partial-v reduce), 8 cols of Wr.
// Data plane: sc0 (XCD-L2) iff startup probe proves coherence, else sc0 sc1.
// Control plane R6: FAST groups store each flag TWICE (sc0 fast + sc1
// backstop); consumers poll sc0 with a periodic sc1 liveness check -> fast
// detection, provably no hang path. SLOW groups: R2-proven sc1-only protocol.

#define TT 1000
#define II 16
#define LL 128
#define HH 512
#define OO 64
#define BB 512

typedef _Float16 f16;
typedef _Float16 f16x8 __attribute__((ext_vector_type(8)));
typedef _Float16 f16x4 __attribute__((ext_vector_type(4)));
typedef float    f32x4 __attribute__((ext_vector_type(4)));
typedef unsigned u32x2 __attribute__((ext_vector_type(2)));
typedef unsigned u32x4 __attribute__((ext_vector_type(4)));

#define MFMA16(a, b, c) __builtin_amdgcn_mfma_f32_16x16x32_f16((a), (b), (c), 0, 0, 0)

#define ZS  520   // act K-stride: z(0..159)/a1(0..511)/vpT(64..191)
#define W1S 168   // K=160 (144 + zero pad)
#define W3S 72    // K=64 (row-slice of W3)
#define WRS 136   // K=128
#define A2S 72    // a2 buffer K-stride
#define HPAD 132  // fp32 h stride

struct Lds {
  f16 w1t[64][W1S];
  f16 w2t[64][ZS];
  f16 w3t[128][W3S];
  f16 wrt[16][WRS];
  f16 act[16][ZS];
  f16 a2s[16][A2S];    // a2 chunk [16 x 64] (separate buffer: no WAR barrier)
  float h[16][HPAD];
  float b1c[64], b2c[64], b3c[128], brc[16];
  int xtmp[8];
};

// ---- always-coherent (L3) primitives ----
__device__ __forceinline__ void st_sc1_u32(void* p, unsigned v) {
  asm volatile("global_store_dword %0, %1, off sc0 sc1" :: "v"(p), "v"(v) : "memory");
}
__device__ __forceinline__ unsigned ld_sc1_u32(const void* p) {
  unsigned r;
  asm volatile("global_load_dword %0, %1, off sc0 sc1\n\ts_waitcnt vmcnt(0)"
               : "=v"(r) : "v"(p) : "memory");
  return r;
}
// ---- XCD-L2 primitives (used only where probe proved coherence) ----
__device__ __forceinline__ void st_sc0_u32(void* p, unsigned v) {
  asm volatile("global_store_dword %0, %1, off sc0" :: "v"(p), "v"(v) : "memory");
}
__device__ __forceinline__ unsigned ld_sc0_u32(const void* p) {
  unsigned r;
  asm volatile("global_load_dword %0, %1, off sc0\n\ts_waitcnt vmcnt(0)"
               : "=v"(r) : "v"(p) : "memory");
  return r;
}
template <bool FAST> __device__ __forceinline__ void st_c_u2(void* p, u32x2 v) {
  if constexpr (FAST) asm volatile("global_store_dwordx2 %0, %1, off sc0"     :: "v"(p), "v"(v) : "memory");
  else                asm volatile("global_store_dwordx2 %0, %1, off sc0 sc1" :: "v"(p), "v"(v) : "memory");
}
template <bool FAST> __device__ __forceinline__ void st_c_u4(void* p, u32x4 v) {
  if constexpr (FAST) asm volatile("global_store_dwordx4 %0, %1, off sc0"     :: "v"(p), "v"(v) : "memory");
  else                asm volatile("global_store_dwordx4 %0, %1, off sc0 sc1" :: "v"(p), "v"(v) : "memory");
}
template <bool FAST> __device__ __forceinline__ u32x4 ld_c_u4(const void* p) {
  u32x4 r;
  if constexpr (FAST) asm volatile("global_load_dwordx4 %0, %1, off sc0"     : "=v"(r) : "v"(p) : "memory");
  else                asm volatile("global_load_dwordx4 %0, %1, off sc0 sc1" : "=v"(r) : "v"(p) : "memory");
  return r;
}
__device__ __forceinline__ void vm_drain() {
  asm volatile("s_waitcnt vmcnt(0)" ::: "memory");
  __builtin_amdgcn_sched_barrier(0);   // rule #18
}

// flag layout per group (stride 64 u32): [0..7] a1 sc0, [8..15] vp sc0,
// [16..23] a1 sc1, [24..31] vp sc1.
template <bool FAST>
__device__ void run_loop(Lds& s, const float* __restrict__ x,
                         float* __restrict__ out, float* __restrict__ lat,
                         unsigned* __restrict__ fl,
                         f16* __restrict__ a1buf, f16* __restrict__ vpbuf,
                         int j, int g, int tid, int w, int lr, int lk) {
  const int r  = tid >> 4;
  const int cg = tid & 15;
  const size_t xoff = (size_t)(g * 16 + r) * TT * II + cg;
  float xr = 0.f;
  float hreg[8] = {0.f, 0.f, 0.f, 0.f, 0.f, 0.f, 0.f, 0.f};

  auto REL = [&](int slot, unsigned val) {
    vm_drain();
    __syncthreads();
    if (tid == 0) {
      if constexpr (FAST) st_sc0_u32(fl + slot * 8 + j, val);
      st_sc1_u32(fl + 16 + slot * 8 + j, val);
    }
  };
  auto WAIT = [&](int slot, unsigned tgt) {
    if (tid < 8) {
      if constexpr (FAST) {
        const unsigned* f0 = fl + slot * 8 + tid;
        const unsigned* f1 = fl + 16 + slot * 8 + tid;
        unsigned c = 0;
        while (ld_sc0_u32(f0) < tgt) {           // fast L2-local poll
          if ((++c & 15u) == 0u && ld_sc1_u32(f1) >= tgt) break;  // liveness
        }
      } else {
        const unsigned* f1 = fl + 16 + slot * 8 + tid;
        while (ld_sc1_u32(f1) < tgt) { }
      }
    }
    __syncthreads();
  };

  for (int t = 0; t < TT; ++t) {
    const int par = t & 1;
    f16* const a1b = a1buf + (size_t)(g * 2 + par) * (16 * 512);
    f16* const vpb = vpbuf + (size_t)(g * 2 + par) * (8 * 16 * 128);

    // -------- phase A: a1_chunk = relu(z @ W1_slice + b1) ------------------
    // swapped operands: lane holds a1[m=lr][n = w*16+4*lk+e] -> one 8B store.
    {
      f32x4 c = {0.f, 0.f, 0.f, 0.f};
#pragma unroll
      for (int kt = 0; kt < 5; ++kt) {
        f16x8 wf = *(const f16x8*)&s.w1t[w * 16 + lr][kt * 32 + lk * 8];
        f16x8 zf = *(const f16x8*)&s.act[lr][kt * 32 + lk * 8];
        c = MFMA16(wf, zf, c);
      }
      f16x4 o;
#pragma unroll
      for (int e = 0; e < 4; ++e) {
        float vv = c[e] + s.b1c[w * 16 + lk * 4 + e];
        vv = vv > 0.f ? vv : 0.f;
        o[e] = (f16)vv;
      }
      st_c_u2<FAST>(a1b + (size_t)lr * 512 + 64 * j + w * 16 + lk * 4,
                    __builtin_bit_cast(u32x2, o));
    }
    REL(0, (unsigned)(t + 1));

    // -------- gap: deferred lat/out stores for t-1, x prefetch -------------
    if (t > 0) {
      if ((cg >> 1) == j) {
        float* dst = lat + ((size_t)(g * 16 + r) * TT + (t - 1)) * LL + cg * 8;
        *(f32x4*)dst = *(f32x4*)&hreg[0];
        *(f32x4*)(dst + 4) = *(f32x4*)&hreg[4];
      }
      if (w == 0) {           // out_{t-1} = h_{t-1} @ Wr + br (act = z_t)
        f32x4 c = {0.f, 0.f, 0.f, 0.f};
#pragma unroll
        for (int kt = 0; kt < 4; ++kt) {
          f16x8 a = *(const f16x8*)&s.act[lr][kt * 32 + lk * 8];
          f16x8 b = *(const f16x8*)&s.wrt[lr][kt * 32 + lk * 8];
          c = MFMA16(a, b, c);
        }
        if (lr < 8) {
#pragma unroll
          for (int e = 0; e < 4; ++e)
            out[((size_t)(g * 16 + lk * 4 + e) * TT + (t - 1)) * OO + 8 * j + lr] =
                c[e] + s.brc[lr];
        }
      }
    }
    xr = (t + 1 < TT) ? x[xoff + (size_t)(t + 1) * II] : 0.f;

    // -------- WAIT a1, stage full a1 [16,512] -> act -----------------------
    WAIT(0, (unsigned)(t + 1));
    {
      u32x4 t0 = ld_c_u4<FAST>(a1b + (size_t)(tid +   0) * 8);
      u32x4 t1 = ld_c_u4<FAST>(a1b + (size_t)(tid + 256) * 8);
      u32x4 t2 = ld_c_u4<FAST>(a1b + (size_t)(tid + 512) * 8);
      u32x4 t3 = ld_c_u4<FAST>(a1b + (size_t)(tid + 768) * 8);
      vm_drain();
      *(u32x4*)&s.act[(tid +   0) >> 6][((tid +   0) & 63) * 8] = t0;
      *(u32x4*)&s.act[(tid + 256) >> 6][((tid + 256) & 63) * 8] = t1;
      *(u32x4*)&s.act[(tid + 512) >> 6][((tid + 512) & 63) * 8] = t2;
      *(u32x4*)&s.act[(tid + 768) >> 6][((tid + 768) & 63) * 8] = t3;
    }
    __syncthreads();

    // -------- phase B: a2_chunk = relu(a1 @ W2_slice + b2) -> a2s ----------
    {
      const int bn = w * 16 + lr;
      f32x4 c0 = {0.f, 0.f, 0.f, 0.f}, c1 = {0.f, 0.f, 0.f, 0.f};
#pragma unroll
      for (int kt = 0; kt < 16; kt += 2) {
        f16x8 a0 = *(const f16x8*)&s.act[lr][kt * 32 + lk * 8];
        f16x8 b0 = *(const f16x8*)&s.w2t[bn][kt * 32 + lk * 8];
        c0 = MFMA16(a0, b0, c0);
        f16x8 a1_ = *(const f16x8*)&s.act[lr][(kt + 1) * 32 + lk * 8];
        f16x8 b1_ = *(const f16x8*)&s.w2t[bn][(kt + 1) * 32 + lk * 8];
        c1 = MFMA16(a1_, b1_, c1);
      }
#pragma unroll
      for (int e = 0; e < 4; ++e) {   // separate buffer: no WAR barrier needed
        float vv = c0[e] + c1[e] + s.b2c[bn];
        vv = vv > 0.f ? vv : 0.f;
        s.a2s[lk * 4 + e][bn] = (f16)vv;
      }
      __syncthreads();
    }

    // -------- phase C: vp = a2_chunk @ W3_rows; LDS-T; coalesced store -----
    {
      const int nt0 = 2 * w, nt1 = 2 * w + 1;
      f32x4 c0 = {0.f, 0.f, 0.f, 0.f}, c1 = {0.f, 0.f, 0.f, 0.f};
#pragma unroll
      for (int kt = 0; kt < 2; ++kt) {
        f16x8 a  = *(const f16x8*)&s.a2s[lr][kt * 32 + lk * 8];
        f16x8 b0 = *(const f16x8*)&s.w3t[nt0 * 16 + lr][kt * 32 + lk * 8];
        c0 = MFMA16(a, b0, c0);
        f16x8 b1_ = *(const f16x8*)&s.w3t[nt1 * 16 + lr][kt * 32 + lk * 8];
        c1 = MFMA16(a, b1_, c1);
      }
#pragma unroll
      for (int e = 0; e < 4; ++e) {   // act a1 fully consumed (post-barrier)
        s.act[lk * 4 + e][64 + nt0 * 16 + lr] = (f16)c0[e];
        s.act[lk * 4 + e][64 + nt1 * 16 + lr] = (f16)c1[e];
      }
      __syncthreads();
      u32x4 v = *(const u32x4*)&s.act[tid >> 4][64 + (tid & 15) * 8];
      st_c_u4<FAST>(vpb + (size_t)j * 2048 + (size_t)tid * 8, v);
    }
    REL(1, (unsigned)(t + 1));
    WAIT(1, (unsigned)(t + 1));

    // -------- phase D: v = sum_j vp_j + b3; h += 0.1 v; rebuild z ----------
    {
      const f16* vb = vpb + (size_t)r * 128 + cg * 8;
      u32x4 p[8];
#pragma unroll
      for (int m = 0; m < 8; ++m) p[m] = ld_c_u4<FAST>(vb + (size_t)m * 2048);
      vm_drain();
      float sum[8] = {0.f, 0.f, 0.f, 0.f, 0.f, 0.f, 0.f, 0.f};
#pragma unroll
      for (int m = 0; m < 8; ++m) {
        f16x8 ph = __builtin_bit_cast(f16x8, p[m]);
#pragma unroll
        for (int e = 0; e < 8; ++e) sum[e] += (float)ph[e];
      }
      f16x8 zf;
#pragma unroll
      for (int e = 0; e < 8; ++e) {
        float hv = s.h[r][cg * 8 + e] + 0.1f * (sum[e] + s.b3c[cg * 8 + e]);
        s.h[r][cg * 8 + e] = hv;
        hreg[e] = hv;
        zf[e] = (f16)hv;
      }
      *(f16x8*)&s.act[r][cg * 8] = zf;
      s.act[r][128 + cg] = (f16)xr;
      s.act[r][144 + cg] = (f16)0.f;
    }
    __syncthreads();
  }

  // -------- epilogue: lat + out for t = TT-1 --------------------------------
  if ((cg >> 1) == j) {
    float* dst = lat + ((size_t)(g * 16 + r) * TT + (TT - 1)) * LL + cg * 8;
    *(f32x4*)dst = *(f32x4*)&hreg[0];
    *(f32x4*)(dst + 4) = *(f32x4*)&hreg[4];
  }
  if (w == 0) {
    f32x4 c = {0.f, 0.f, 0.f, 0.f};
#pragma unroll
    for (int kt = 0; kt < 4; ++kt) {
      f16x8 a = *(const f16x8*)&s.act[lr][kt * 32 + lk * 8];
      f16x8 b = *(const f16x8*)&s.wrt[lr][kt * 32 + lk * 8];
      c = MFMA16(a, b, c);
    }
    if (lr < 8) {
#pragma unroll
      for (int e = 0; e < 4; ++e)
        out[((size_t)(g * 16 + lk * 4 + e) * TT + (TT - 1)) * OO + 8 * j + lr] =
            c[e] + s.brc[lr];
    }
  }
}

__launch_bounds__(256, 1)
__global__ void node_scan_kernel(
    const float* __restrict__ x,
    const float* __restrict__ W1, const float* __restrict__ b1,
    const float* __restrict__ W2, const float* __restrict__ b2,
    const float* __restrict__ W3, const float* __restrict__ b3,
    const float* __restrict__ Wr, const float* __restrict__ br,
    float* __restrict__ out,
    unsigned* __restrict__ flags, unsigned* __restrict__ xccbuf,
    unsigned* __restrict__ pflag, unsigned* __restrict__ pack,
    unsigned* __restrict__ verd,  unsigned* __restrict__ pdata,
    f16* __restrict__ a1buf, f16* __restrict__ vpbuf)
{
  __shared__ Lds s;
  const int tid  = threadIdx.x;
  const int bid  = blockIdx.x;
  const int q    = bid >> 3;
  const int j    = q & 7;
  const int g    = (bid & 7) + 8 * (q >> 3);    // group 0..31 (co-XCD heuristic)
  const int lane = tid & 63;
  const int w    = tid >> 6;
  const int lr   = lane & 15;
  const int lk   = lane >> 4;

  float* lat = out + (size_t)BB * TT * OO;

  // ---------------- prologue: weights -> LDS (transposed, f16) ------------
  { int n = tid & 63, ks = tid >> 6;
    for (int k = ks; k < 144; k += 4)       s.w1t[n][k] = (f16)W1[(size_t)k * HH + 64 * j + n];
    for (int k = 144 + ks; k < W1S; k += 4) s.w1t[n][k] = (f16)0.f;
    for (int k = ks; k < HH; k += 4)        s.w2t[n][k] = (f16)W2[(size_t)k * HH + 64 * j + n];
  }
  for (int idx = tid; idx < 128 * 64; idx += 256) {
    int kl = idx >> 7, n = idx & 127;
    s.w3t[n][kl] = (f16)W3[(size_t)(64 * j + kl) * LL + n];
  }
  { int n = tid & 15, ks = tid >> 4;
    for (int k = ks; k < LL; k += 16)
      s.wrt[n][k] = (n < 8) ? (f16)Wr[(size_t)k * OO + 8 * j + n] : (f16)0.f;
  }
  if (tid < 64)       { s.b1c[tid] = b1[64 * j + tid]; s.b2c[tid] = b2[64 * j + tid]; }
  else if (tid < 192) { s.b3c[tid - 64] = b3[tid - 64]; }
  else if (tid < 208) { int n = tid - 192; s.brc[n] = (n < 8) ? br[8 * j + n] : 0.f; }
  for (int i = tid; i < 16 * HPAD; i += 256) ((float*)s.h)[i] = 0.f;
  for (int i = tid; i < 16 * ZS; i += 256) ((f16*)s.act)[i] = (f16)0.f;

  // ---------------- XCD-placement exchange (sc1, proven live) --------------
  int xcc;
  asm volatile("s_getreg_b32 %0, hwreg(HW_REG_XCC_ID)" : "=s"(xcc));
  xcc &= 15;
  if (tid == 0) { st_sc1_u32(xccbuf + g * 8 + j, 0x100u | (unsigned)xcc); vm_drain(); }
  if (tid < 8) {
    unsigned v;
    const unsigned* p = xccbuf + g * 8 + tid;
    do { v = ld_sc1_u32(p); } while (!(v & 0x100u));
    s.xtmp[tid] = (int)(v & 0xffu);
  }
  __syncthreads();
  bool fast = true;
  for (int k2 = 1; k2 < 8; ++k2) fast = fast && (s.xtmp[k2] == s.xtmp[0]);

  // ---------------- sc0 coherence probe (3 rounds, no sc0 spin) ------------
  unsigned okbit = 1u;
  if (fast) {
    unsigned* pd = pdata + g * 8;
    unsigned* pf = pflag + g * 8;
    unsigned* pa = pack  + g * 8;
    const unsigned X = 0x51A00000u | ((unsigned)j << 4);
#pragma unroll 1
    for (int rnd = 0; rnd < 3; ++rnd) {
      unsigned val = (rnd == 1) ? (X | 1u) : X;   // rnd2 restores X
      if (tid == 0) {
        st_sc0_u32(pd + j, val);
        vm_drain();
        st_sc1_u32(pf + j, (unsigned)(rnd + 1));
        vm_drain();
      }
      if (tid < 8) {
        while (ld_sc1_u32(pf + tid) < (unsigned)(rnd + 1)) { }
        if (rnd < 2) {   // rnd0 warms L1 (if bypass broken); rnd1 detects stale
          unsigned exp = 0x51A00000u | ((unsigned)tid << 4) | (rnd == 1 ? 1u : 0u);
          if (ld_sc0_u32(pd + tid) != exp) okbit = 0u;
        }
      }
      __syncthreads();
      if (tid == 0) { st_sc1_u32(pa + j, (unsigned)(rnd + 1)); vm_drain(); }
      if (tid < 8) { while (ld_sc1_u32(pa + tid) < (unsigned)(rnd + 1)) { } }
      __syncthreads();
    }
    if (tid < 8) s.xtmp[tid] = (int)okbit;
    __syncthreads();
    for (int k2 = 0; k2 < 8; ++k2) fast = fast && (s.xtmp[k2] != 0);
  }
  // ---------------- verdict exchange: group-uniform FAST/SLOW --------------
  if (tid == 0) { st_sc1_u32(verd + g * 8 + j, 0x100u | (fast ? 1u : 0u)); vm_drain(); }
  if (tid < 8) {
    unsigned v;
    const unsigned* p = verd + g * 8 + tid;
    do { v = ld_sc1_u32(p); } while (!(v & 0x100u));
    s.xtmp[tid] = (int)(v & 1u);
  }
  __syncthreads();
  bool FASTRUN = true;
  for (int k2 = 0; k2 < 8; ++k2) FASTRUN = FASTRUN && (s.xtmp[k2] != 0);

  // z_0 = [0 | x_0 | 0]
  { const int r = tid >> 4, cc = tid & 15;
    s.act[r][128 + cc] = (f16)x[(size_t)(g * 16 + r) * TT * II + cc]; }
  __syncthreads();

  unsigned* const fl = flags + g * 64;
  if (FASTRUN) run_loop<true >(s, x, out, lat, fl, a1buf, vpbuf, j, g, tid, w, lr, lk);
  else         run_loop<false>(s, x, out, lat, fl, a1buf, vpbuf, j, g, tid, w, lr, lk);
}

extern "C" void kernel_launch(void* const* d_in, const int* in_sizes, int n_in,
                              void* d_out, int out_size, void* d_ws, size_t ws_size,
                              hipStream_t stream) {
  const float* x  = (const float*)d_in[0];
  const float* W1 = (const float*)d_in[1];
  const float* b1 = (const float*)d_in[2];
  const float* W2 = (const float*)d_in[3];
  const float* b2 = (const float*)d_in[4];
  const float* W3 = (const float*)d_in[5];
  const float* b3 = (const float*)d_in[6];
  const float* Wr = (const float*)d_in[7];
  const float* br = (const float*)d_in[8];
  float* out = (float*)d_out;

  // ws: [0,8K) flags | [8K) xcc | [9K) pflag | [10K) pack | [11K) verd   (all
  // sc1-written, memset 0 each launch) | [12K,13K) pdata (sc0, NOT memset —
  // probe round 3 restores it) | [16K) 1MB a1buf | 2MB vpbuf
  unsigned* flags  = (unsigned*)d_ws;
  unsigned* xccbuf = (unsigned*)((char*)d_ws + 8192);
  unsigned* pflag  = (unsigned*)((char*)d_ws + 9216);
  unsigned* pack   = (unsigned*)((char*)d_ws + 10240);
  unsigned* verd   = (unsigned*)((char*)d_ws + 11264);
  unsigned* pdata  = (unsigned*)((char*)d_ws + 12288);
  f16* a1buf = (f16*)((char*)d_ws + 16384);
  f16* vpbuf = (f16*)((char*)d_ws + 16384 + (1 << 20));

  hipMemsetAsync(d_ws, 0, 12288, stream);  // flags/xcc/pflag/pack/verd only
  node_scan_kernel<<<256, 256, 0, stream>>>(x, W1, b1, W2, b2, W3, b3, Wr, br,
                                            out, flags, xccbuf, pflag, pack,
                                            verd, pdata, a1buf, vpbuf);
}

// Round 8
// 5154.900 us; speedup vs baseline: 1.2709x; 1.2709x over previous
//
#include <hip/hip_runtime.h>

// NODE scan: 32 groups x 8 blocks; group = 16 batch rows; block j owns a
// 64-col slice of W1/W2, 64-ROW slice of W3 (partial-v reduce), 8 cols of Wr.
// R8 = R7 with the w1t swizzle-overflow fixed: XOR swizzle (byte^=(row&7)<<4)
// permutes within 128B blocks, so EVERY row stride must be a multiple of
// 128B. W1S 176->192 f16 (384B = 3x128). All else identical to R7:
// swizzled LDS, phase-B a1 fragments direct from L2, per-wave polls,
// wave-local vpT store, h in registers, 4 barriers/step.
// Flags: sc1 (L3, proven live). Data: sc0 iff startup probe proves it.

#define TT 1000
#define II 16
#define LL 128
#define HH 512
#define OO 64
#define BB 512

typedef _Float16 f16;
typedef _Float16 f16x8 __attribute__((ext_vector_type(8)));
typedef _Float16 f16x4 __attribute__((ext_vector_type(4)));
typedef float    f32x4 __attribute__((ext_vector_type(4)));
typedef unsigned u32x2 __attribute__((ext_vector_type(2)));
typedef unsigned u32x4 __attribute__((ext_vector_type(4)));

#define MFMA16(a, b, c) __builtin_amdgcn_mfma_f32_16x16x32_f16((a), (b), (c), 0, 0, 0)

// f16 row strides: row byte-size MUST be a multiple of 128 (XOR block size).
#define ZS2  256   // 512B: z 0..159 | vpT 64..191 | a2 192..255
#define W1S  192   // 384B = 3*128 (K=160 used; 144 data + 16 zero pad)
#define W2S  512   // 1024B
#define W3S  64    // 128B
#define WRS  128   // 256B

// swizzled address: row-base + (2*colf16 ^ ((row&7)<<4))
#define SWB(rowptr, row, colf16) \
  ((void*)((char*)(rowptr) + ((2 * (colf16)) ^ (((row) & 7) << 4))))

struct Lds {
  f16 w1t[64][W1S];
  f16 w2t[64][W2S];
  f16 w3t[128][W3S];
  f16 wrt[16][WRS];
  f16 act[16][ZS2];
  float b1c[64], b2c[64], b3c[128], brc[16];
  int xtmp[8];
};

// ---- always-coherent (L3) primitives ----
__device__ __forceinline__ void st_sc1_u32(void* p, unsigned v) {
  asm volatile("global_store_dword %0, %1, off sc0 sc1" :: "v"(p), "v"(v) : "memory");
}
__device__ __forceinline__ unsigned ld_sc1_u32(const void* p) {
  unsigned r;
  asm volatile("global_load_dword %0, %1, off sc0 sc1\n\ts_waitcnt vmcnt(0)"
               : "=v"(r) : "v"(p) : "memory");
  return r;
}
// ---- XCD-L2 primitives (used only where probe proved coherence) ----
__device__ __forceinline__ void st_sc0_u32(void* p, unsigned v) {
  asm volatile("global_store_dword %0, %1, off sc0" :: "v"(p), "v"(v) : "memory");
}
__device__ __forceinline__ unsigned ld_sc0_u32(const void* p) {
  unsigned r;
  asm volatile("global_load_dword %0, %1, off sc0\n\ts_waitcnt vmcnt(0)"
               : "=v"(r) : "v"(p) : "memory");
  return r;
}
template <bool FAST> __device__ __forceinline__ void st_c_u2(void* p, u32x2 v) {
  if constexpr (FAST) asm volatile("global_store_dwordx2 %0, %1, off sc0"     :: "v"(p), "v"(v) : "memory");
  else                asm volatile("global_store_dwordx2 %0, %1, off sc0 sc1" :: "v"(p), "v"(v) : "memory");
}
template <bool FAST> __device__ __forceinline__ void st_c_u4(void* p, u32x4 v) {
  if constexpr (FAST) asm volatile("global_store_dwordx4 %0, %1, off sc0"     :: "v"(p), "v"(v) : "memory");
  else                asm volatile("global_store_dwordx4 %0, %1, off sc0 sc1" :: "v"(p), "v"(v) : "memory");
}
template <bool FAST> __device__ __forceinline__ u32x4 ld_c_u4(const void* p) {
  u32x4 r;
  if constexpr (FAST) asm volatile("global_load_dwordx4 %0, %1, off sc0"     : "=v"(r) : "v"(p) : "memory");
  else                asm volatile("global_load_dwordx4 %0, %1, off sc0 sc1" : "=v"(r) : "v"(p) : "memory");
  return r;
}
__device__ __forceinline__ void vm_drain() {
  asm volatile("s_waitcnt vmcnt(0)" ::: "memory");
  __builtin_amdgcn_sched_barrier(0);   // rule #18
}

// flag layout per group (stride 256 u32): a1 flag j at [j*16], vp at [128+j*16]
template <bool FAST>
__device__ void run_loop(Lds& s, const float* __restrict__ x,
                         float* __restrict__ out, float* __restrict__ lat,
                         unsigned* __restrict__ fl,
                         f16* __restrict__ a1buf, f16* __restrict__ vpbuf,
                         int j, int g, int tid, int w, int lr, int lk) {
  const int r    = tid >> 4;
  const int cg   = tid & 15;
  const int lane = tid & 63;
  const size_t xoff = (size_t)(g * 16 + r) * TT * II + cg;
  float xr = 0.f;
  float hreg[8] = {0.f, 0.f, 0.f, 0.f, 0.f, 0.f, 0.f, 0.f};

  for (int t = 0; t < TT; ++t) {
    const int par = t & 1;
    f16* const a1b = a1buf + (size_t)(g * 2 + par) * (16 * 512);
    f16* const vpb = vpbuf + (size_t)(g * 2 + par) * (8 * 16 * 128);

    // -------- phase A: a1_chunk = relu(z @ W1_slice + b1) ------------------
    {
      const int n = w * 16 + lr;
      f32x4 c = {0.f, 0.f, 0.f, 0.f};
#pragma unroll
      for (int kt = 0; kt < 5; ++kt) {
        f16x8 wf = *(const f16x8*)SWB(&s.w1t[n][0], n, kt * 32 + lk * 8);
        f16x8 zf = *(const f16x8*)SWB(&s.act[lr][0], lr, kt * 32 + lk * 8);
        c = MFMA16(wf, zf, c);
      }
      f16x4 o;
#pragma unroll
      for (int e = 0; e < 4; ++e) {
        float vv = c[e] + s.b1c[w * 16 + lk * 4 + e];
        vv = vv > 0.f ? vv : 0.f;
        o[e] = (f16)vv;
      }
      st_c_u2<FAST>(a1b + (size_t)lr * 512 + 64 * j + w * 16 + lk * 4,
                    __builtin_bit_cast(u32x2, o));
    }
    vm_drain();
    __syncthreads();
    if (tid == 0) st_sc1_u32(fl + j * 16, (unsigned)(t + 1));

    // -------- gap0: out_{t-1} = h_{t-1} @ Wr + br (act-z = h_{t-1}|x_t) ----
    if (t > 0 && w == 0) {
      f32x4 c = {0.f, 0.f, 0.f, 0.f};
#pragma unroll
      for (int kt = 0; kt < 4; ++kt) {
        f16x8 a = *(const f16x8*)SWB(&s.act[lr][0], lr, kt * 32 + lk * 8);
        f16x8 b = *(const f16x8*)SWB(&s.wrt[lr][0], lr, kt * 32 + lk * 8);
        c = MFMA16(a, b, c);
      }
      if (lr < 8) {
#pragma unroll
        for (int e = 0; e < 4; ++e)
          out[((size_t)(g * 16 + lk * 4 + e) * TT + (t - 1)) * OO + 8 * j + lr] =
              c[e] + s.brc[lr];
      }
    }

    // -------- per-wave poll a1 flags, B reads fragments DIRECT from L2 -----
    if (lane < 8) {
      const unsigned* fp = fl + lane * 16;
      while (ld_sc1_u32(fp) < (unsigned)(t + 1)) { }
    }
    {
      const int bn = w * 16 + lr;
      u32x4 araw[16];
#pragma unroll
      for (int kt = 0; kt < 16; ++kt)
        araw[kt] = ld_c_u4<FAST>(a1b + (size_t)lr * 512 + kt * 32 + lk * 8);
      vm_drain();
      f32x4 c0 = {0.f, 0.f, 0.f, 0.f}, c1 = {0.f, 0.f, 0.f, 0.f};
#pragma unroll
      for (int kt = 0; kt < 16; kt += 2) {
        f16x8 b0 = *(const f16x8*)SWB(&s.w2t[bn][0], bn, kt * 32 + lk * 8);
        c0 = MFMA16(__builtin_bit_cast(f16x8, araw[kt]), b0, c0);
        f16x8 b1_ = *(const f16x8*)SWB(&s.w2t[bn][0], bn, (kt + 1) * 32 + lk * 8);
        c1 = MFMA16(__builtin_bit_cast(f16x8, araw[kt + 1]), b1_, c1);
      }
#pragma unroll
      for (int e = 0; e < 4; ++e) {           // a2 chunk -> act cols 192..255
        float vv = c0[e] + c1[e] + s.b2c[bn];
        vv = vv > 0.f ? vv : 0.f;
        *(f16*)SWB(&s.act[lk * 4 + e][0], lk * 4 + e, 192 + bn) = (f16)vv;
      }
    }
    __syncthreads();   // a2 visible to all waves

    // -------- phase C: vp = a2 @ W3_rows; wave-local vpT + store -----------
    {
      const int nt0 = 2 * w, nt1 = 2 * w + 1;
      f32x4 c0 = {0.f, 0.f, 0.f, 0.f}, c1 = {0.f, 0.f, 0.f, 0.f};
#pragma unroll
      for (int kt = 0; kt < 2; ++kt) {
        f16x8 a = *(const f16x8*)SWB(&s.act[lr][0], lr, 192 + kt * 32 + lk * 8);
        f16x8 b0 = *(const f16x8*)SWB(&s.w3t[nt0 * 16 + lr][0], nt0 * 16 + lr, kt * 32 + lk * 8);
        c0 = MFMA16(a, b0, c0);
        f16x8 b1_ = *(const f16x8*)SWB(&s.w3t[nt1 * 16 + lr][0], nt1 * 16 + lr, kt * 32 + lk * 8);
        c1 = MFMA16(a, b1_, c1);
      }
#pragma unroll
      for (int e = 0; e < 4; ++e) {           // vpT cols 64+32w..64+32w+31
        *(f16*)SWB(&s.act[lk * 4 + e][0], lk * 4 + e, 64 + nt0 * 16 + lr) = (f16)c0[e];
        *(f16*)SWB(&s.act[lk * 4 + e][0], lk * 4 + e, 64 + nt1 * 16 + lr) = (f16)c1[e];
      }
      // wave stores ONLY the cols it wrote (no barrier needed)
      const int vr = lane >> 2, vc = (lane & 3) * 8;
      u32x4 vv = *(const u32x4*)SWB(&s.act[vr][0], vr, 64 + 32 * w + vc);
      st_c_u4<FAST>(vpb + (size_t)j * 2048 + (size_t)vr * 128 + 32 * w + vc, vv);
    }
    vm_drain();
    __syncthreads();
    if (tid == 0) st_sc1_u32(fl + 128 + j * 16, (unsigned)(t + 1));

    // -------- gap1: lat stores for t-1 (hreg only) + x prefetch ------------
    if (t > 0 && (cg >> 1) == j) {
      float* dst = lat + ((size_t)(g * 16 + r) * TT + (t - 1)) * LL + cg * 8;
      *(f32x4*)dst = *(f32x4*)&hreg[0];
      *(f32x4*)(dst + 4) = *(f32x4*)&hreg[4];
    }
    xr = (t + 1 < TT) ? x[xoff + (size_t)(t + 1) * II] : 0.f;

    // -------- per-wave poll vp flags -------------------------------------
    if (lane < 8) {
      const unsigned* fp = fl + 128 + lane * 16;
      while (ld_sc1_u32(fp) < (unsigned)(t + 1)) { }
    }

    // -------- phase D: v = sum_j vp_j + b3; h += 0.1v; rebuild z -----------
    {
      const f16* vb = vpb + (size_t)r * 128 + cg * 8;
      u32x4 p[8];
#pragma unroll
      for (int m = 0; m < 8; ++m) p[m] = ld_c_u4<FAST>(vb + (size_t)m * 2048);
      vm_drain();
      float sum[8] = {0.f, 0.f, 0.f, 0.f, 0.f, 0.f, 0.f, 0.f};
#pragma unroll
      for (int m = 0; m < 8; ++m) {
        f16x8 ph = __builtin_bit_cast(f16x8, p[m]);
#pragma unroll
        for (int e = 0; e < 8; ++e) sum[e] += (float)ph[e];
      }
      f16x8 zf;
#pragma unroll
      for (int e = 0; e < 8; ++e) {
        hreg[e] += 0.1f * (sum[e] + s.b3c[cg * 8 + e]);
        zf[e] = (f16)hreg[e];
      }
      *(f16x8*)SWB(&s.act[r][0], r, cg * 8) = zf;
      *(f16*)SWB(&s.act[r][0], r, 128 + cg) = (f16)xr;
      *(f16*)SWB(&s.act[r][0], r, 144 + cg) = (f16)0.f;   // re-zero K pad
    }
    __syncthreads();   // z ready for next A
  }

  // -------- epilogue: lat + out for t = TT-1 --------------------------------
  if ((cg >> 1) == j) {
    float* dst = lat + ((size_t)(g * 16 + r) * TT + (TT - 1)) * LL + cg * 8;
    *(f32x4*)dst = *(f32x4*)&hreg[0];
    *(f32x4*)(dst + 4) = *(f32x4*)&hreg[4];
  }
  if (w == 0) {
    f32x4 c = {0.f, 0.f, 0.f, 0.f};
#pragma unroll
    for (int kt = 0; kt < 4; ++kt) {
      f16x8 a = *(const f16x8*)SWB(&s.act[lr][0], lr, kt * 32 + lk * 8);
      f16x8 b = *(const f16x8*)SWB(&s.wrt[lr][0], lr, kt * 32 + lk * 8);
      c = MFMA16(a, b, c);
    }
    if (lr < 8) {
#pragma unroll
      for (int e = 0; e < 4; ++e)
        out[((size_t)(g * 16 + lk * 4 + e) * TT + (TT - 1)) * OO + 8 * j + lr] =
            c[e] + s.brc[lr];
    }
  }
}

__launch_bounds__(256, 1)
__global__ void node_scan_kernel(
    const float* __restrict__ x,
    const float* __restrict__ W1, const float* __restrict__ b1,
    const float* __restrict__ W2, const float* __restrict__ b2,
    const float* __restrict__ W3, const float* __restrict__ b3,
    const float* __restrict__ Wr, const float* __restrict__ br,
    float* __restrict__ out,
    unsigned* __restrict__ flags, unsigned* __restrict__ xccbuf,
    unsigned* __restrict__ pflag, unsigned* __restrict__ pack,
    unsigned* __restrict__ verd,  unsigned* __restrict__ pdata,
    f16* __restrict__ a1buf, f16* __restrict__ vpbuf)
{
  __shared__ Lds s;
  const int tid  = threadIdx.x;
  const int bid  = blockIdx.x;
  const int q    = bid >> 3;
  const int j    = q & 7;
  const int g    = (bid & 7) + 8 * (q >> 3);    // group 0..31 (co-XCD heuristic)
  const int lane = tid & 63;
  const int w    = tid >> 6;
  const int lr   = lane & 15;
  const int lk   = lane >> 4;

  float* lat = out + (size_t)BB * TT * OO;

  // ---------------- prologue: weights -> LDS (transposed, f16, swizzled) ---
  { int n = tid & 63, ks = tid >> 6;
    for (int k = ks; k < 144; k += 4)
      *(f16*)SWB(&s.w1t[n][0], n, k) = (f16)W1[(size_t)k * HH + 64 * j + n];
    for (int k = 144 + ks; k < 160; k += 4)
      *(f16*)SWB(&s.w1t[n][0], n, k) = (f16)0.f;
    for (int k = ks; k < HH; k += 4)
      *(f16*)SWB(&s.w2t[n][0], n, k) = (f16)W2[(size_t)k * HH + 64 * j + n];
  }
  for (int idx = tid; idx < 128 * 64; idx += 256) {
    int kl = idx >> 7, n = idx & 127;
    *(f16*)SWB(&s.w3t[n][0], n, kl) = (f16)W3[(size_t)(64 * j + kl) * LL + n];
  }
  { int n = tid & 15, ks = tid >> 4;
    for (int k = ks; k < LL; k += 16)
      *(f16*)SWB(&s.wrt[n][0], n, k) =
          (n < 8) ? (f16)Wr[(size_t)k * OO + 8 * j + n] : (f16)0.f;
  }
  if (tid < 64)       { s.b1c[tid] = b1[64 * j + tid]; s.b2c[tid] = b2[64 * j + tid]; }
  else if (tid < 192) { s.b3c[tid - 64] = b3[tid - 64]; }
  else if (tid < 208) { int n = tid - 192; s.brc[n] = (n < 8) ? br[8 * j + n] : 0.f; }
  for (int i = tid; i < 16 * ZS2; i += 256) ((f16*)s.act)[i] = (f16)0.f;

  // ---------------- XCD-placement exchange (sc1, proven live) --------------
  int xcc;
  asm volatile("s_getreg_b32 %0, hwreg(HW_REG_XCC_ID)" : "=s"(xcc));
  xcc &= 15;
  if (tid == 0) { st_sc1_u32(xccbuf + g * 8 + j, 0x100u | (unsigned)xcc); vm_drain(); }
  if (tid < 8) {
    unsigned v;
    const unsigned* p = xccbuf + g * 8 + tid;
    do { v = ld_sc1_u32(p); } while (!(v & 0x100u));
    s.xtmp[tid] = (int)(v & 0xffu);
  }
  __syncthreads();
  bool fast = true;
  for (int k2 = 1; k2 < 8; ++k2) fast = fast && (s.xtmp[k2] == s.xtmp[0]);

  // ---------------- sc0 coherence probe (3 rounds, no sc0 spin) ------------
  unsigned okbit = 1u;
  if (fast) {
    unsigned* pd = pdata + g * 8;
    unsigned* pf = pflag + g * 8;
    unsigned* pa = pack  + g * 8;
    const unsigned X = 0x51A00000u | ((unsigned)j << 4);
#pragma unroll 1
    for (int rnd = 0; rnd < 3; ++rnd) {
      unsigned val = (rnd == 1) ? (X | 1u) : X;   // rnd2 restores X
      if (tid == 0) {
        st_sc0_u32(pd + j, val);
        vm_drain();
        st_sc1_u32(pf + j, (unsigned)(rnd + 1));
        vm_drain();
      }
      if (tid < 8) {
        while (ld_sc1_u32(pf + tid) < (unsigned)(rnd + 1)) { }
        if (rnd < 2) {
          unsigned exp = 0x51A00000u | ((unsigned)tid << 4) | (rnd == 1 ? 1u : 0u);
          if (ld_sc0_u32(pd + tid) != exp) okbit = 0u;
        }
      }
      __syncthreads();
      if (tid == 0) { st_sc1_u32(pa + j, (unsigned)(rnd + 1)); vm_drain(); }
      if (tid < 8) { while (ld_sc1_u32(pa + tid) < (unsigned)(rnd + 1)) { } }
      __syncthreads();
    }
    if (tid < 8) s.xtmp[tid] = (int)okbit;
    __syncthreads();
    for (int k2 = 0; k2 < 8; ++k2) fast = fast && (s.xtmp[k2] != 0);
  }
  // ---------------- verdict exchange: group-uniform FAST/SLOW --------------
  if (tid == 0) { st_sc1_u32(verd + g * 8 + j, 0x100u | (fast ? 1u : 0u)); vm_drain(); }
  if (tid < 8) {
    unsigned v;
    const unsigned* p = verd + g * 8 + tid;
    do { v = ld_sc1_u32(p); } while (!(v & 0x100u));
    s.xtmp[tid] = (int)(v & 1u);
  }
  __syncthreads();
  bool FASTRUN = true;
  for (int k2 = 0; k2 < 8; ++k2) FASTRUN = FASTRUN && (s.xtmp[k2] != 0);

  // z_0 = [0 | x_0 | 0]
  { const int rr = tid >> 4, cc = tid & 15;
    *(f16*)SWB(&s.act[rr][0], rr, 128 + cc) =
        (f16)x[(size_t)(g * 16 + rr) * TT * II + cc]; }
  __syncthreads();

  unsigned* const fl = flags + g * 256;
  if (FASTRUN) run_loop<true >(s, x, out, lat, fl, a1buf, vpbuf, j, g, tid, w, lr, lk);
  else         run_loop<false>(s, x, out, lat, fl, a1buf, vpbuf, j, g, tid, w, lr, lk);
}

extern "C" void kernel_launch(void* const* d_in, const int* in_sizes, int n_in,
                              void* d_out, int out_size, void* d_ws, size_t ws_size,
                              hipStream_t stream) {
  const float* x  = (const float*)d_in[0];
  const float* W1 = (const float*)d_in[1];
  const float* b1 = (const float*)d_in[2];
  const float* W2 = (const float*)d_in[3];
  const float* b2 = (const float*)d_in[4];
  const float* W3 = (const float*)d_in[5];
  const float* b3 = (const float*)d_in[6];
  const float* Wr = (const float*)d_in[7];
  const float* br = (const float*)d_in[8];
  float* out = (float*)d_out;

  // ws: [0,32K) flags (32 groups x 256 u32, line-spread) | [32K) xcc |
  // [33K) pflag | [34K) pack | [35K) verd  (memset 0..36K each launch) |
  // [36K,37K) pdata (sc0 probe, NOT memset; rnd2 restores) |
  // [64K) 1MB a1buf | [64K+1M) 2MB vpbuf
  unsigned* flags  = (unsigned*)d_ws;
  unsigned* xccbuf = (unsigned*)((char*)d_ws + 32768);
  unsigned* pflag  = (unsigned*)((char*)d_ws + 33792);
  unsigned* pack   = (unsigned*)((char*)d_ws + 34816);
  unsigned* verd   = (unsigned*)((char*)d_ws + 35840);
  unsigned* pdata  = (unsigned*)((char*)d_ws + 36864);
  f16* a1buf = (f16*)((char*)d_ws + 65536);
  f16* vpbuf = (f16*)((char*)d_ws + 65536 + (1 << 20));

  hipMemsetAsync(d_ws, 0, 36864, stream);  // flags/xcc/pflag/pack/verd only
  node_scan_kernel<<<256, 256, 0, stream>>>(x, W1, b1, W2, b2, W3, b3, Wr, br,
                                            out, flags, xccbuf, pflag, pack,
                                            verd, pdata, a1buf, vpbuf);
}